// Round 1
// baseline (2448.196 us; speedup 1.0000x reference)
//
#include <hip/hip_runtime.h>
#include <math.h>

#define B_ 4
#define L_ 64
#define D_ 512
#define DI_ 1024
#define N_ 16
#define DC_ 4
#define R_ 32
#define NL_ 4
#define SD_ 17
#define AD_ 6
#define T_ 256   // 4*L

__device__ __forceinline__ float silu_f(float v) { return v / (1.f + expf(-v)); }
__device__ __forceinline__ float softplus_f(float v) {
    return fmaxf(v, 0.f) + log1pf(expf(-fabsf(v)));
}

// ---------------------------------------------------------------------------
// Embedding: build x (B, T=256, D) from r,c,s,a token embeddings + time emb
// one block per (b,l), 512 threads = one per d
// ---------------------------------------------------------------------------
__global__ __launch_bounds__(512) void embed_kernel(
    const float* __restrict__ states, const float* __restrict__ actions,
    const float* __restrict__ rtg, const float* __restrict__ ctg,
    const int* __restrict__ ts,
    const float* __restrict__ es_w, const float* __restrict__ es_b,
    const float* __restrict__ ea_w, const float* __restrict__ ea_b,
    const float* __restrict__ er_w, const float* __restrict__ er_b,
    const float* __restrict__ ec_w, const float* __restrict__ ec_b,
    const float* __restrict__ et_w, float* __restrict__ x)
{
    const int bl = blockIdx.x;           // 0..255 = b*64+l
    const int d = threadIdx.x;           // 0..511
    const float te = et_w[(size_t)ts[bl] * D_ + d];
    const float r = rtg[bl] * er_w[d] + er_b[d] + te;
    const float c = ctg[bl] * ec_w[d] + ec_b[d] + te;
    float s = es_b[d] + te;
#pragma unroll
    for (int k = 0; k < SD_; ++k) s += states[bl * SD_ + k] * es_w[d * SD_ + k];
    float a = ea_b[d] + te;
#pragma unroll
    for (int k = 0; k < AD_; ++k) a += actions[bl * AD_ + k] * ea_w[d * AD_ + k];
    float* xp = x + (size_t)bl * 4 * D_;   // token (b, 4l+k)
    xp[0 * D_ + d] = r;
    xp[1 * D_ + d] = c;
    xp[2 * D_ + d] = s;
    xp[3 * D_ + d] = a;
}

// ---------------------------------------------------------------------------
// LayerNorm over D=512; one block (256 thr) per token, 2 elems/thread
// ---------------------------------------------------------------------------
__global__ __launch_bounds__(256) void ln_kernel(
    const float* __restrict__ x, const float* __restrict__ w,
    const float* __restrict__ b, float* __restrict__ o)
{
    const int tok = blockIdx.x;
    const int tid = threadIdx.x;
    const float2 v = reinterpret_cast<const float2*>(x + (size_t)tok * D_)[tid];
    float s = v.x + v.y;
#pragma unroll
    for (int off = 1; off < 64; off <<= 1) s += __shfl_xor(s, off);
    __shared__ float red[8];
    const int wv = tid >> 6;
    if ((tid & 63) == 0) red[wv] = s;
    __syncthreads();
    const float mean = (red[0] + red[1] + red[2] + red[3]) * (1.f / D_);
    const float dx = v.x - mean, dy = v.y - mean;
    float q = dx * dx + dy * dy;
#pragma unroll
    for (int off = 1; off < 64; off <<= 1) q += __shfl_xor(q, off);
    if ((tid & 63) == 0) red[4 + wv] = q;
    __syncthreads();
    const float var = (red[4] + red[5] + red[6] + red[7]) * (1.f / D_);
    const float r = rsqrtf(var + 1e-5f);
    const int d0 = tid * 2;
    o[(size_t)tok * D_ + d0]     = dx * r * w[d0] + b[d0];
    o[(size_t)tok * D_ + d0 + 1] = dy * r * w[d0 + 1] + b[d0 + 1];
}

// ---------------------------------------------------------------------------
// GEMM: C[M,N] = A[M,K](lda) @ W[N,K]^T  (+ epilogue)
// EPI 0: store; 1: softplus(val + bias[n]); 2: C += val (residual)
// 64x64 block tile, BK=16, 256 threads, 4x4 per thread
// ---------------------------------------------------------------------------
template <int EPI>
__global__ __launch_bounds__(256) void gemm_nt(
    const float* __restrict__ A, int lda,
    const float* __restrict__ W, const float* __restrict__ bias,
    float* __restrict__ C, int M, int N, int K)
{
    constexpr int BM = 64, BN = 64, BK = 16;
    __shared__ float As[BK][BM + 1];
    __shared__ float Ws[BK][BN + 1];
    const int bm = blockIdx.y * BM, bn = blockIdx.x * BN;
    const int tid = threadIdx.x;
    const int tx = tid & 15, ty = tid >> 4;
    float acc[4][4] = {};
    for (int k0 = 0; k0 < K; k0 += BK) {
        for (int i = tid; i < BM * BK; i += 256) {
            const int m = i >> 4, k = i & 15;
            As[k][m] = A[(size_t)(bm + m) * lda + k0 + k];
        }
        for (int i = tid; i < BN * BK; i += 256) {
            const int n = i >> 4, k = i & 15;
            Ws[k][n] = W[(size_t)(bn + n) * K + k0 + k];
        }
        __syncthreads();
#pragma unroll
        for (int k = 0; k < BK; ++k) {
            float a[4], w[4];
#pragma unroll
            for (int u = 0; u < 4; ++u) a[u] = As[k][ty * 4 + u];
#pragma unroll
            for (int v = 0; v < 4; ++v) w[v] = Ws[k][tx * 4 + v];
#pragma unroll
            for (int u = 0; u < 4; ++u)
#pragma unroll
                for (int v = 0; v < 4; ++v) acc[u][v] += a[u] * w[v];
        }
        __syncthreads();
    }
#pragma unroll
    for (int u = 0; u < 4; ++u)
#pragma unroll
        for (int v = 0; v < 4; ++v) {
            const int m = bm + ty * 4 + u, n = bn + tx * 4 + v;
            float val = acc[u][v];
            if (EPI == 1) val = softplus_f(val + bias[n]);
            if (EPI == 2) C[(size_t)m * N + n] += val;
            else          C[(size_t)m * N + n] = val;
        }
}

// ---------------------------------------------------------------------------
// Causal depthwise conv1d (DC=4) + SiLU.  xm = xz[:, :, :DI]
// one thread per (b,t,d)
// ---------------------------------------------------------------------------
__global__ __launch_bounds__(256) void conv_silu_kernel(
    const float* __restrict__ xz, const float* __restrict__ cw,
    const float* __restrict__ cb, float* __restrict__ xc)
{
    const int idx = blockIdx.x * 256 + threadIdx.x;  // d fastest
    const int d = idx & (DI_ - 1);
    const int bt = idx >> 10;            // b*T + t
    const int t = bt & (T_ - 1);
    float acc = cb[d];
#pragma unroll
    for (int k = 0; k < DC_; ++k) {
        const int tt = t - (DC_ - 1) + k;
        if (tt >= 0) acc += cw[d * DC_ + k] * xz[(size_t)(bt - t + tt) * 2 * DI_ + d];
    }
    xc[idx] = silu_f(acc);
}

// ---------------------------------------------------------------------------
// Selective scan + output gating.
// 16 lanes per (b,d) channel (one per state n); 16 channels per 256-thr block.
// yg[b,t,d] = (sum_n h*C + u*Dp) * silu(z)
// ---------------------------------------------------------------------------
__global__ __launch_bounds__(256) void scan_gate_kernel(
    const float* __restrict__ dlt, const float* __restrict__ xc,
    const float* __restrict__ dbc, const float* __restrict__ xz,
    const float* __restrict__ A_log, const float* __restrict__ Dp,
    float* __restrict__ yg)
{
    const int tid = threadIdx.x;
    const int n = tid & 15;
    const int grp = tid >> 4;
    const int pair = blockIdx.x * 16 + grp;   // 0..4095
    const int b = pair >> 10;
    const int d = pair & (DI_ - 1);
    const float Av = -expf(A_log[d * N_ + n]);
    const float Dd = Dp[d];
    const float* dl = dlt + (size_t)b * T_ * DI_ + d;
    const float* up = xc + (size_t)b * T_ * DI_ + d;
    const float* bc = dbc + (size_t)b * T_ * (R_ + 2 * N_);
    const float* zp = xz + (size_t)b * T_ * 2 * DI_ + DI_ + d;
    float* yp = yg + (size_t)b * T_ * DI_ + d;
    float h = 0.f;
    for (int t = 0; t < T_; ++t) {
        const float dt = dl[(size_t)t * DI_];
        const float ut = up[(size_t)t * DI_];
        const float Bn = bc[t * 64 + R_ + n];
        const float Cn = bc[t * 64 + R_ + N_ + n];
        h = expf(dt * Av) * h + dt * Bn * ut;
        float p = h * Cn;
        p += __shfl_xor(p, 1);
        p += __shfl_xor(p, 2);
        p += __shfl_xor(p, 4);
        p += __shfl_xor(p, 8);
        if (n == 0) {
            const float zv = zp[(size_t)t * 2 * DI_];
            yp[(size_t)t * DI_] = (p + ut * Dd) * silu_f(zv);
        }
    }
}

// ---------------------------------------------------------------------------
// Heads: state_preds (B,L,17) from token 4l+3; action_preds (B,L,6) from 4l+2
// one wave (64 lanes) per output scalar
// ---------------------------------------------------------------------------
__global__ __launch_bounds__(256) void heads_kernel(
    const float* __restrict__ xn,
    const float* __restrict__ ps_w, const float* __restrict__ ps_b,
    const float* __restrict__ pa_w, const float* __restrict__ pa_b,
    float* __restrict__ out)
{
    const int idx = blockIdx.x * 4 + (threadIdx.x >> 6);  // 0..5887
    const int lane = threadIdx.x & 63;
    const int bl = idx / 23, j = idx % 23;
    const float* tok;
    const float* wrow;
    float bias;
    float* dst;
    if (j < SD_) {
        tok = xn + ((size_t)bl * 4 + 3) * D_;
        wrow = ps_w + (size_t)j * D_;
        bias = ps_b[j];
        dst = out + (size_t)bl * SD_ + j;
    } else {
        const int jj = j - SD_;
        tok = xn + ((size_t)bl * 4 + 2) * D_;
        wrow = pa_w + (size_t)jj * D_;
        bias = pa_b[jj];
        dst = out + (size_t)B_ * L_ * SD_ + (size_t)bl * AD_ + jj;
    }
    float s = 0.f;
    for (int dd = lane; dd < D_; dd += 64) s += tok[dd] * wrow[dd];
#pragma unroll
    for (int off = 1; off < 64; off <<= 1) s += __shfl_xor(s, off);
    if (lane == 0) *dst = s + bias;
}

// ---------------------------------------------------------------------------
extern "C" void kernel_launch(void* const* d_in, const int* in_sizes, int n_in,
                              void* d_out, int out_size, void* d_ws, size_t ws_size,
                              hipStream_t stream)
{
    const float* states  = (const float*)d_in[0];
    const float* actions = (const float*)d_in[1];
    const float* rtg     = (const float*)d_in[2];
    const float* ctg     = (const float*)d_in[3];
    const int*   ts      = (const int*)d_in[4];
    const float* es_w = (const float*)d_in[5];  const float* es_b = (const float*)d_in[6];
    const float* ea_w = (const float*)d_in[7];  const float* ea_b = (const float*)d_in[8];
    const float* er_w = (const float*)d_in[9];  const float* er_b = (const float*)d_in[10];
    const float* ec_w = (const float*)d_in[11]; const float* ec_b = (const float*)d_in[12];
    const float* et_w = (const float*)d_in[13];
    const float* ln_w = (const float*)d_in[14]; const float* ln_b = (const float*)d_in[15];
    const float* in_w = (const float*)d_in[16];
    const float* conv_w = (const float*)d_in[17]; const float* conv_b = (const float*)d_in[18];
    const float* xp_w = (const float*)d_in[19];
    const float* dtp_w = (const float*)d_in[20]; const float* dtp_b = (const float*)d_in[21];
    const float* A_log = (const float*)d_in[22]; const float* Dp = (const float*)d_in[23];
    const float* out_w = (const float*)d_in[24];
    const float* fn_w = (const float*)d_in[25]; const float* fn_b = (const float*)d_in[26];
    const float* ps_w = (const float*)d_in[27]; const float* ps_b = (const float*)d_in[28];
    const float* pa_w = (const float*)d_in[29]; const float* pa_b = (const float*)d_in[30];
    float* out = (float*)d_out;

    float* ws  = (float*)d_ws;
    float* x   = ws;                 // B*T*D      = 524288
    float* xn  = x  + 524288;        // B*T*D      = 524288
    float* xz  = xn + 524288;        // B*T*2DI    = 2097152
    float* xc  = xz + 2097152;       // B*T*DI     = 1048576
    float* dbc = xc + 1048576;       // B*T*64     = 65536
    float* dlt = dbc + 65536;        // B*T*DI     = 1048576
    float* yg  = dlt + 1048576;      // B*T*DI     = 1048576

    embed_kernel<<<B_ * L_, D_, 0, stream>>>(states, actions, rtg, ctg, ts,
        es_w, es_b, ea_w, ea_b, er_w, er_b, ec_w, ec_b, et_w, x);

    for (int i = 0; i < NL_; ++i) {
        ln_kernel<<<B_ * T_, 256, 0, stream>>>(x, ln_w + i * D_, ln_b + i * D_, xn);
        // xz = xn @ in_w^T   (1024 x 2048 x 512)
        gemm_nt<0><<<dim3(2 * DI_ / 64, B_ * T_ / 64), 256, 0, stream>>>(
            xn, D_, in_w + (size_t)i * 2 * DI_ * D_, nullptr, xz, B_ * T_, 2 * DI_, D_);
        conv_silu_kernel<<<(B_ * T_ * DI_) / 256, 256, 0, stream>>>(
            xz, conv_w + i * DI_ * DC_, conv_b + i * DI_, xc);
        // dbc = xc @ xp_w^T  (1024 x 64 x 1024)
        gemm_nt<0><<<dim3(1, B_ * T_ / 64), 256, 0, stream>>>(
            xc, DI_, xp_w + (size_t)i * (R_ + 2 * N_) * DI_, nullptr, dbc, B_ * T_, R_ + 2 * N_, DI_);
        // delta = softplus(dt @ dtp_w^T + dtp_b)  (1024 x 1024 x 32), dt = dbc[:, :32]
        gemm_nt<1><<<dim3(DI_ / 64, B_ * T_ / 64), 256, 0, stream>>>(
            dbc, R_ + 2 * N_, dtp_w + (size_t)i * DI_ * R_, dtp_b + i * DI_, dlt, B_ * T_, DI_, R_);
        scan_gate_kernel<<<(B_ * DI_) / 16, 256, 0, stream>>>(
            dlt, xc, dbc, xz, A_log + (size_t)i * DI_ * N_, Dp + i * DI_, yg);
        // x += yg @ out_w^T  (1024 x 512 x 1024)
        gemm_nt<2><<<dim3(D_ / 64, B_ * T_ / 64), 256, 0, stream>>>(
            yg, DI_, out_w + (size_t)i * D_ * DI_, nullptr, x, B_ * T_, D_, DI_);
    }

    ln_kernel<<<B_ * T_, 256, 0, stream>>>(x, fn_w, fn_b, xn);
    heads_kernel<<<(B_ * L_ * 23) / 4, 256, 0, stream>>>(xn, ps_w, ps_b, pa_w, pa_b, out);
}

// Round 2
// 446.491 us; speedup vs baseline: 5.4832x; 5.4832x over previous
//
#include <hip/hip_runtime.h>
#include <math.h>

#define B_ 4
#define L_ 64
#define D_ 512
#define DI_ 1024
#define N_ 16
#define DC_ 4
#define R_ 32
#define NL_ 4
#define SD_ 17
#define AD_ 6
#define T_ 256   // 4*L
#define CH_ 8    // scan chunks
#define TC_ 32   // T_/CH_

typedef short bf16x8 __attribute__((ext_vector_type(8)));
typedef float f32x4 __attribute__((ext_vector_type(4)));

__device__ __forceinline__ float silu_f(float v) { return v / (1.f + __expf(-v)); }
__device__ __forceinline__ float softplus_f(float v) {
    return fmaxf(v, 0.f) + log1pf(__expf(-fabsf(v)));
}
// fp32 -> bf16 (RNE, no NaN handling — inputs are finite)
__device__ __forceinline__ unsigned short f2bs(float f) {
    unsigned u = __float_as_uint(f);
    u += 0x7fffu + ((u >> 16) & 1u);
    return (unsigned short)(u >> 16);
}
__device__ __forceinline__ float bs2f(unsigned short s) {
    return __uint_as_float(((unsigned)s) << 16);
}
__device__ __forceinline__ bf16x8 cvt8(float4 lo, float4 hi) {
    bf16x8 o;
    o[0] = (short)f2bs(lo.x); o[1] = (short)f2bs(lo.y);
    o[2] = (short)f2bs(lo.z); o[3] = (short)f2bs(lo.w);
    o[4] = (short)f2bs(hi.x); o[5] = (short)f2bs(hi.y);
    o[6] = (short)f2bs(hi.z); o[7] = (short)f2bs(hi.w);
    return o;
}

// ---------------------------------------------------------------------------
// Embedding: build x (B, T=256, D) from r,c,s,a token embeddings + time emb
// ---------------------------------------------------------------------------
__global__ __launch_bounds__(512) void embed_kernel(
    const float* __restrict__ states, const float* __restrict__ actions,
    const float* __restrict__ rtg, const float* __restrict__ ctg,
    const int* __restrict__ ts,
    const float* __restrict__ es_w, const float* __restrict__ es_b,
    const float* __restrict__ ea_w, const float* __restrict__ ea_b,
    const float* __restrict__ er_w, const float* __restrict__ er_b,
    const float* __restrict__ ec_w, const float* __restrict__ ec_b,
    const float* __restrict__ et_w, float* __restrict__ x)
{
    const int bl = blockIdx.x;
    const int d = threadIdx.x;
    const float te = et_w[(size_t)ts[bl] * D_ + d];
    const float r = rtg[bl] * er_w[d] + er_b[d] + te;
    const float c = ctg[bl] * ec_w[d] + ec_b[d] + te;
    float s = es_b[d] + te;
#pragma unroll
    for (int k = 0; k < SD_; ++k) s += states[bl * SD_ + k] * es_w[d * SD_ + k];
    float a = ea_b[d] + te;
#pragma unroll
    for (int k = 0; k < AD_; ++k) a += actions[bl * AD_ + k] * ea_w[d * AD_ + k];
    float* xp = x + (size_t)bl * 4 * D_;
    xp[0 * D_ + d] = r;
    xp[1 * D_ + d] = c;
    xp[2 * D_ + d] = s;
    xp[3 * D_ + d] = a;
}

// ---------------------------------------------------------------------------
// LayerNorm over D=512; one block (256 thr) per token. BF16OUT -> ushort buf
// ---------------------------------------------------------------------------
template <bool BF16OUT>
__global__ __launch_bounds__(256) void ln_kernel(
    const float* __restrict__ x, const float* __restrict__ w,
    const float* __restrict__ b, void* __restrict__ o_)
{
    const int tok = blockIdx.x;
    const int tid = threadIdx.x;
    const float2 v = reinterpret_cast<const float2*>(x + (size_t)tok * D_)[tid];
    float s = v.x + v.y;
#pragma unroll
    for (int off = 1; off < 64; off <<= 1) s += __shfl_xor(s, off);
    __shared__ float red[8];
    const int wv = tid >> 6;
    if ((tid & 63) == 0) red[wv] = s;
    __syncthreads();
    const float mean = (red[0] + red[1] + red[2] + red[3]) * (1.f / D_);
    const float dx = v.x - mean, dy = v.y - mean;
    float q = dx * dx + dy * dy;
#pragma unroll
    for (int off = 1; off < 64; off <<= 1) q += __shfl_xor(q, off);
    if ((tid & 63) == 0) red[4 + wv] = q;
    __syncthreads();
    const float var = (red[4] + red[5] + red[6] + red[7]) * (1.f / D_);
    const float r = rsqrtf(var + 1e-5f);
    const int d0 = tid * 2;
    const float o0 = dx * r * w[d0] + b[d0];
    const float o1 = dy * r * w[d0 + 1] + b[d0 + 1];
    if (BF16OUT) {
        unsigned short* o = (unsigned short*)o_;
        o[(size_t)tok * D_ + d0] = f2bs(o0);
        o[(size_t)tok * D_ + d0 + 1] = f2bs(o1);
    } else {
        float* o = (float*)o_;
        o[(size_t)tok * D_ + d0] = o0;
        o[(size_t)tok * D_ + d0 + 1] = o1;
    }
}

// ---------------------------------------------------------------------------
// MFMA bf16 GEMM: C[M,N] = A[M,K] @ W[N,K]^T (+epilogue). No LDS: fragments
// stream from L1/L2 (weights/activations are cache-resident at these sizes).
// 4 waves per block in 2x2; each wave does (MR*16)x(NR*16).
// EPI 0: store fp32; 1: softplus(val + bias[n]); 2: C += val (residual)
// AF32: A is fp32 (convert on the fly); else A is bf16 (ushort)
// ---------------------------------------------------------------------------
template <int MR, int NR, int EPI, bool AF32>
__global__ __launch_bounds__(256) void gemm_mfma(
    const void* __restrict__ A_, int lda,
    const float* __restrict__ W, const float* __restrict__ bias,
    float* __restrict__ C, int N, int K)
{
    const int lane = threadIdx.x & 63, wid = threadIdx.x >> 6;
    const int r = lane & 15, kq = lane >> 4;
    const int wm = blockIdx.y * (2 * MR * 16) + (wid >> 1) * (MR * 16);
    const int wn = blockIdx.x * (2 * NR * 16) + (wid & 1) * (NR * 16);
    const float* Af = (const float*)A_;
    const unsigned short* Ab = (const unsigned short*)A_;
    f32x4 acc[MR][NR] = {};
    for (int k0 = 0; k0 < K; k0 += 32) {
        bf16x8 a[MR], b[NR];
#pragma unroll
        for (int i = 0; i < MR; ++i) {
            const int row = wm + i * 16 + r;
            if (AF32) {
                const float4* p = (const float4*)(Af + (size_t)row * lda + k0 + kq * 8);
                a[i] = cvt8(p[0], p[1]);
            } else {
                a[i] = *(const bf16x8*)(Ab + (size_t)row * lda + k0 + kq * 8);
            }
        }
#pragma unroll
        for (int j = 0; j < NR; ++j) {
            const int row = wn + j * 16 + r;
            const float4* p = (const float4*)(W + (size_t)row * K + k0 + kq * 8);
            b[j] = cvt8(p[0], p[1]);
        }
#pragma unroll
        for (int i = 0; i < MR; ++i)
#pragma unroll
            for (int j = 0; j < NR; ++j)
                acc[i][j] = __builtin_amdgcn_mfma_f32_16x16x32_bf16(a[i], b[j], acc[i][j], 0, 0, 0);
    }
    // C/D layout: col = lane&15, row = (lane>>4)*4 + reg   [verified m89/m91]
#pragma unroll
    for (int i = 0; i < MR; ++i)
#pragma unroll
        for (int j = 0; j < NR; ++j)
#pragma unroll
            for (int g = 0; g < 4; ++g) {
                const int row = wm + i * 16 + kq * 4 + g;
                const int col = wn + j * 16 + r;
                float val = acc[i][j][g];
                if (EPI == 1) val = softplus_f(val + bias[col]);
                if (EPI == 2) C[(size_t)row * N + col] += val;
                else          C[(size_t)row * N + col] = val;
            }
}

// ---------------------------------------------------------------------------
// xp GEMM with split-K=8: dbc_part[s] = xc[:, sK:(s+1)K] @ xp_w[:, sK:]^T
// one wave per (nt, mt, split) 16x16 tile-chunk; then reduce.
// ---------------------------------------------------------------------------
__global__ __launch_bounds__(256) void xp_split_kernel(
    const unsigned short* __restrict__ xcb, const float* __restrict__ W,
    float* __restrict__ part)
{
    const int w = blockIdx.x * 4 + (threadIdx.x >> 6);   // 0..2047
    const int lane = threadIdx.x & 63;
    const int r = lane & 15, kq = lane >> 4;
    const int split = w & 7, mt = (w >> 3) & 63, nt = w >> 9;
    f32x4 acc = {};
    const int k00 = split * 128;
#pragma unroll
    for (int ks = 0; ks < 4; ++ks) {
        const int k0 = k00 + ks * 32;
        bf16x8 a = *(const bf16x8*)(xcb + (size_t)(mt * 16 + r) * DI_ + k0 + kq * 8);
        const float4* p = (const float4*)(W + (size_t)(nt * 16 + r) * DI_ + k0 + kq * 8);
        bf16x8 b = cvt8(p[0], p[1]);
        acc = __builtin_amdgcn_mfma_f32_16x16x32_bf16(a, b, acc, 0, 0, 0);
    }
    float* dst = part + (size_t)split * 65536;
#pragma unroll
    for (int g = 0; g < 4; ++g)
        dst[(size_t)(mt * 16 + kq * 4 + g) * 64 + nt * 16 + r] = acc[g];
}

__global__ __launch_bounds__(256) void xp_reduce_kernel(
    const float* __restrict__ part, float* __restrict__ dbc)
{
    const int i = blockIdx.x * 256 + threadIdx.x;   // 65536
    float s = 0.f;
#pragma unroll
    for (int c = 0; c < 8; ++c) s += part[(size_t)c * 65536 + i];
    dbc[i] = s;
}

// ---------------------------------------------------------------------------
// Causal depthwise conv1d (DC=4) + SiLU -> bf16
// ---------------------------------------------------------------------------
__global__ __launch_bounds__(256) void conv_silu_kernel(
    const float* __restrict__ xz, const float* __restrict__ cw,
    const float* __restrict__ cb, unsigned short* __restrict__ xcb)
{
    const int idx = blockIdx.x * 256 + threadIdx.x;
    const int d = idx & (DI_ - 1);
    const int bt = idx >> 10;
    const int t = bt & (T_ - 1);
    float acc = cb[d];
#pragma unroll
    for (int k = 0; k < DC_; ++k) {
        const int tt = t - (DC_ - 1) + k;
        if (tt >= 0) acc += cw[d * DC_ + k] * xz[(size_t)(bt - t + tt) * 2 * DI_ + d];
    }
    xcb[idx] = f2bs(silu_f(acc));
}

// ---------------------------------------------------------------------------
// Chunked selective scan. Group = 16 lanes (one per state n) per (b,c,d).
// g = (b*8+c)*1024 + d  -> consecutive groups share (b,c), consecutive d.
// pass1: local scan h0=0 over chunk -> S (local final), P (prod of dA)
// pass2: sequential combine over chunks: S[c] <- h_in[c]
// pass3: full scan per chunk from h_in, y = (sum_n h*C + u*Dp)*silu(z) -> bf16
// ---------------------------------------------------------------------------
__global__ __launch_bounds__(256) void scan_p1_kernel(
    const float* __restrict__ dlt, const unsigned short* __restrict__ xcb,
    const float* __restrict__ dbc, const float* __restrict__ A_log,
    float* __restrict__ P, float* __restrict__ S)
{
    const int tid = threadIdx.x;
    const int n = tid & 15;
    const int g = blockIdx.x * 16 + (tid >> 4);
    const int d = g & (DI_ - 1);
    const int c = (g >> 10) & 7;
    const int b = g >> 13;
    const float Av = -__expf(A_log[d * N_ + n]);
    const int t0 = c * TC_;
    const float* dl = dlt + ((size_t)b * T_ + t0) * DI_ + d;
    const unsigned short* up = xcb + ((size_t)b * T_ + t0) * DI_ + d;
    const float* bc = dbc + ((size_t)b * T_ + t0) * 64;
    float h = 0.f, Pp = 1.f;
#pragma unroll 4
    for (int t = 0; t < TC_; ++t) {
        const float dt = dl[(size_t)t * DI_];
        const float ut = bs2f(up[(size_t)t * DI_]);
        const float Bn = bc[t * 64 + R_ + n];
        const float dA = __expf(dt * Av);
        h = dA * h + dt * Bn * ut;
        Pp *= dA;
    }
    P[(size_t)g * 16 + n] = Pp;
    S[(size_t)g * 16 + n] = h;
}

__global__ __launch_bounds__(256) void scan_p2_kernel(
    const float* __restrict__ P, float* __restrict__ S)
{
    const int i = blockIdx.x * 256 + threadIdx.x;   // 65536 = B*DI*N
    const int n = i & 15, d = (i >> 4) & (DI_ - 1), b = i >> 14;
    float h = 0.f;
#pragma unroll
    for (int c = 0; c < CH_; ++c) {
        const size_t idx = ((size_t)((b * 8 + c) * 1024 + d)) * 16 + n;
        const float t = P[idx] * h + S[idx];
        S[idx] = h;          // S[c] becomes h_in for chunk c
        h = t;
    }
}

__global__ __launch_bounds__(256) void scan_p3_kernel(
    const float* __restrict__ dlt, const unsigned short* __restrict__ xcb,
    const float* __restrict__ dbc, const float* __restrict__ xz,
    const float* __restrict__ A_log, const float* __restrict__ Dp,
    const float* __restrict__ S, unsigned short* __restrict__ ygb)
{
    const int tid = threadIdx.x;
    const int n = tid & 15;
    const int g = blockIdx.x * 16 + (tid >> 4);
    const int d = g & (DI_ - 1);
    const int c = (g >> 10) & 7;
    const int b = g >> 13;
    const float Av = -__expf(A_log[d * N_ + n]);
    const float Dd = Dp[d];
    const int t0 = c * TC_;
    const float* dl = dlt + ((size_t)b * T_ + t0) * DI_ + d;
    const unsigned short* up = xcb + ((size_t)b * T_ + t0) * DI_ + d;
    const float* bc = dbc + ((size_t)b * T_ + t0) * 64;
    const float* zp = xz + ((size_t)b * T_ + t0) * 2 * DI_ + DI_ + d;
    unsigned short* yp = ygb + ((size_t)b * T_ + t0) * DI_ + d;
    float h = S[(size_t)g * 16 + n];
#pragma unroll 4
    for (int t = 0; t < TC_; ++t) {
        const float dt = dl[(size_t)t * DI_];
        const float ut = bs2f(up[(size_t)t * DI_]);
        const float Bn = bc[t * 64 + R_ + n];
        const float Cn = bc[t * 64 + R_ + N_ + n];
        h = __expf(dt * Av) * h + dt * Bn * ut;
        float p = h * Cn;
        p += __shfl_xor(p, 1);
        p += __shfl_xor(p, 2);
        p += __shfl_xor(p, 4);
        p += __shfl_xor(p, 8);
        if (n == 0) {
            const float zv = zp[(size_t)t * 2 * DI_];
            yp[(size_t)t * DI_] = f2bs((p + ut * Dd) * silu_f(zv));
        }
    }
}

// ---------------------------------------------------------------------------
// Heads: state_preds from action tokens (4l+3), action_preds from state (4l+2)
// ---------------------------------------------------------------------------
__global__ __launch_bounds__(256) void heads_kernel(
    const float* __restrict__ xn,
    const float* __restrict__ ps_w, const float* __restrict__ ps_b,
    const float* __restrict__ pa_w, const float* __restrict__ pa_b,
    float* __restrict__ out)
{
    const int idx = blockIdx.x * 4 + (threadIdx.x >> 6);
    const int lane = threadIdx.x & 63;
    const int bl = idx / 23, j = idx % 23;
    const float* tok;
    const float* wrow;
    float bias;
    float* dst;
    if (j < SD_) {
        tok = xn + ((size_t)bl * 4 + 3) * D_;
        wrow = ps_w + (size_t)j * D_;
        bias = ps_b[j];
        dst = out + (size_t)bl * SD_ + j;
    } else {
        const int jj = j - SD_;
        tok = xn + ((size_t)bl * 4 + 2) * D_;
        wrow = pa_w + (size_t)jj * D_;
        bias = pa_b[jj];
        dst = out + (size_t)B_ * L_ * SD_ + (size_t)bl * AD_ + jj;
    }
    float s = 0.f;
    for (int dd = lane; dd < D_; dd += 64) s += tok[dd] * wrow[dd];
#pragma unroll
    for (int off = 1; off < 64; off <<= 1) s += __shfl_xor(s, off);
    if (lane == 0) *dst = s + bias;
}

// ---------------------------------------------------------------------------
extern "C" void kernel_launch(void* const* d_in, const int* in_sizes, int n_in,
                              void* d_out, int out_size, void* d_ws, size_t ws_size,
                              hipStream_t stream)
{
    const float* states  = (const float*)d_in[0];
    const float* actions = (const float*)d_in[1];
    const float* rtg     = (const float*)d_in[2];
    const float* ctg     = (const float*)d_in[3];
    const int*   ts      = (const int*)d_in[4];
    const float* es_w = (const float*)d_in[5];  const float* es_b = (const float*)d_in[6];
    const float* ea_w = (const float*)d_in[7];  const float* ea_b = (const float*)d_in[8];
    const float* er_w = (const float*)d_in[9];  const float* er_b = (const float*)d_in[10];
    const float* ec_w = (const float*)d_in[11]; const float* ec_b = (const float*)d_in[12];
    const float* et_w = (const float*)d_in[13];
    const float* ln_w = (const float*)d_in[14]; const float* ln_b = (const float*)d_in[15];
    const float* in_w = (const float*)d_in[16];
    const float* conv_w = (const float*)d_in[17]; const float* conv_b = (const float*)d_in[18];
    const float* xp_w = (const float*)d_in[19];
    const float* dtp_w = (const float*)d_in[20]; const float* dtp_b = (const float*)d_in[21];
    const float* A_log = (const float*)d_in[22]; const float* Dp = (const float*)d_in[23];
    const float* out_w = (const float*)d_in[24];
    const float* fn_w = (const float*)d_in[25]; const float* fn_b = (const float*)d_in[26];
    const float* ps_w = (const float*)d_in[27]; const float* ps_b = (const float*)d_in[28];
    const float* pa_w = (const float*)d_in[29]; const float* pa_b = (const float*)d_in[30];
    float* out = (float*)d_out;

    // workspace (floats): total 24.3 MB
    float* ws   = (float*)d_ws;
    float* x    = ws;                   // 524288
    float* xn   = x + 524288;           // 524288 (fp32 final LN; P aliases during layers)
    float* P    = xn;                   // alias: 524288, dead before final LN
    float* xz   = xn + 524288;          // 2097152
    float* dbc  = xz + 2097152;         // 65536
    float* dlt  = dbc + 65536;          // 1048576 (dbc_part aliases: 524288, dead before dtp)
    float* part = dlt;                  // alias
    float* S    = dlt + 1048576;        // 524288
    unsigned short* xnb = (unsigned short*)(S + 524288);  // 524288 elems bf16
    unsigned short* xcb = xnb + 524288;                   // 1048576 elems bf16
    unsigned short* ygb = xcb + 1048576;                  // 1048576 elems bf16

    embed_kernel<<<B_ * L_, D_, 0, stream>>>(states, actions, rtg, ctg, ts,
        es_w, es_b, ea_w, ea_b, er_w, er_b, ec_w, ec_b, et_w, x);

    for (int i = 0; i < NL_; ++i) {
        ln_kernel<true><<<B_ * T_, 256, 0, stream>>>(x, ln_w + i * D_, ln_b + i * D_, xnb);
        // xz = xn @ in_w^T   (1024 x 2048 x 512)
        gemm_mfma<2, 2, 0, false><<<dim3(32, 16), 256, 0, stream>>>(
            xnb, D_, in_w + (size_t)i * 2 * DI_ * D_, nullptr, xz, 2 * DI_, D_);
        conv_silu_kernel<<<(B_ * T_ * DI_) / 256, 256, 0, stream>>>(
            xz, conv_w + i * DI_ * DC_, conv_b + i * DI_, xcb);
        // dbc = xc @ xp_w^T  (1024 x 64 x 1024), split-K=8
        xp_split_kernel<<<512, 256, 0, stream>>>(xcb, xp_w + (size_t)i * 64 * DI_, part);
        xp_reduce_kernel<<<256, 256, 0, stream>>>(part, dbc);
        // delta = softplus(dbc[:, :32] @ dtp_w^T + dtp_b)  (1024 x 1024 x 32)
        gemm_mfma<2, 2, 1, true><<<dim3(16, 16), 256, 0, stream>>>(
            dbc, 64, dtp_w + (size_t)i * DI_ * R_, dtp_b + i * DI_, dlt, DI_, R_);
        // chunked selective scan + gate
        scan_p1_kernel<<<2048, 256, 0, stream>>>(
            dlt, xcb, dbc, A_log + (size_t)i * DI_ * N_, P, S);
        scan_p2_kernel<<<256, 256, 0, stream>>>(P, S);
        scan_p3_kernel<<<2048, 256, 0, stream>>>(
            dlt, xcb, dbc, xz, A_log + (size_t)i * DI_ * N_, Dp + i * DI_, S, ygb);
        // x += yg @ out_w^T  (1024 x 512 x 1024)
        gemm_mfma<2, 1, 2, false><<<dim3(16, 16), 256, 0, stream>>>(
            ygb, DI_, out_w + (size_t)i * D_ * DI_, nullptr, x, D_, DI_);
    }

    ln_kernel<false><<<B_ * T_, 256, 0, stream>>>(x, fn_w, fn_b, xn);
    heads_kernel<<<(B_ * L_ * 23) / 4, 256, 0, stream>>>(xn, ps_w, ps_b, pa_w, pa_b, out);
}

// Round 3
// 384.744 us; speedup vs baseline: 6.3632x; 1.1605x over previous
//
#include <hip/hip_runtime.h>
#include <math.h>

#define B_ 4
#define L_ 64
#define D_ 512
#define DI_ 1024
#define N_ 16
#define DC_ 4
#define R_ 32
#define NL_ 4
#define SD_ 17
#define AD_ 6
#define T_ 256   // 4*L
#define CH_ 8    // scan chunks
#define TC_ 32   // T_/CH_

// weight segment sizes (elements)
#define NW_IN  (NL_ * 2 * DI_ * D_)   // 4194304
#define NW_OUT (NL_ * D_ * DI_)       // 2097152
#define NW_XP  (NL_ * 64 * DI_)       // 262144
#define NW_DTP (NL_ * DI_ * R_)       // 131072
#define NW_TOT (NW_IN + NW_OUT + NW_XP + NW_DTP)  // 6684672

typedef short bf16x8 __attribute__((ext_vector_type(8)));
typedef float f32x4 __attribute__((ext_vector_type(4)));

__device__ __forceinline__ float silu_f(float v) { return v / (1.f + __expf(-v)); }
__device__ __forceinline__ float softplus_f(float v) {
    return fmaxf(v, 0.f) + log1pf(__expf(-fabsf(v)));
}
__device__ __forceinline__ unsigned short f2bs(float f) {
    unsigned u = __float_as_uint(f);
    u += 0x7fffu + ((u >> 16) & 1u);
    return (unsigned short)(u >> 16);
}
__device__ __forceinline__ float bs2f(unsigned short s) {
    return __uint_as_float(((unsigned)s) << 16);
}
__device__ __forceinline__ bf16x8 cvt8(float4 lo, float4 hi) {
    bf16x8 o;
    o[0] = (short)f2bs(lo.x); o[1] = (short)f2bs(lo.y);
    o[2] = (short)f2bs(lo.z); o[3] = (short)f2bs(lo.w);
    o[4] = (short)f2bs(hi.x); o[5] = (short)f2bs(hi.y);
    o[6] = (short)f2bs(hi.z); o[7] = (short)f2bs(hi.w);
    return o;
}

// ---------------------------------------------------------------------------
// One-time: convert all layer weights fp32 -> bf16 into wb (segment order:
// in_w | out_w | xp_w | dtp_w). 4 floats per thread.
// ---------------------------------------------------------------------------
__global__ __launch_bounds__(256) void wcvt_kernel(
    const float* __restrict__ in_w, const float* __restrict__ out_w,
    const float* __restrict__ xp_w, const float* __restrict__ dtp_w,
    unsigned short* __restrict__ wb)
{
    const int i = blockIdx.x * 256 + threadIdx.x;   // float4 index
    if (i >= NW_TOT / 4) return;
    const int e = i * 4;
    const float* src; int off;
    if (e < NW_IN)                  { src = in_w;  off = e; }
    else if (e < NW_IN + NW_OUT)    { src = out_w; off = e - NW_IN; }
    else if (e < NW_IN + NW_OUT + NW_XP) { src = xp_w; off = e - NW_IN - NW_OUT; }
    else                            { src = dtp_w; off = e - NW_IN - NW_OUT - NW_XP; }
    const float4 v = *(const float4*)(src + off);
    ushort4 o;
    o.x = f2bs(v.x); o.y = f2bs(v.y); o.z = f2bs(v.z); o.w = f2bs(v.w);
    *(ushort4*)(wb + e) = o;
}

// ---------------------------------------------------------------------------
// Embedding
// ---------------------------------------------------------------------------
__global__ __launch_bounds__(512) void embed_kernel(
    const float* __restrict__ states, const float* __restrict__ actions,
    const float* __restrict__ rtg, const float* __restrict__ ctg,
    const int* __restrict__ ts,
    const float* __restrict__ es_w, const float* __restrict__ es_b,
    const float* __restrict__ ea_w, const float* __restrict__ ea_b,
    const float* __restrict__ er_w, const float* __restrict__ er_b,
    const float* __restrict__ ec_w, const float* __restrict__ ec_b,
    const float* __restrict__ et_w, float* __restrict__ x)
{
    const int bl = blockIdx.x;
    const int d = threadIdx.x;
    const float te = et_w[(size_t)ts[bl] * D_ + d];
    const float r = rtg[bl] * er_w[d] + er_b[d] + te;
    const float c = ctg[bl] * ec_w[d] + ec_b[d] + te;
    float s = es_b[d] + te;
#pragma unroll
    for (int k = 0; k < SD_; ++k) s += states[bl * SD_ + k] * es_w[d * SD_ + k];
    float a = ea_b[d] + te;
#pragma unroll
    for (int k = 0; k < AD_; ++k) a += actions[bl * AD_ + k] * ea_w[d * AD_ + k];
    float* xp = x + (size_t)bl * 4 * D_;
    xp[0 * D_ + d] = r;
    xp[1 * D_ + d] = c;
    xp[2 * D_ + d] = s;
    xp[3 * D_ + d] = a;
}

// ---------------------------------------------------------------------------
// LayerNorm over D=512; one block (256 thr) per token
// ---------------------------------------------------------------------------
template <bool BF16OUT>
__global__ __launch_bounds__(256) void ln_kernel(
    const float* __restrict__ x, const float* __restrict__ w,
    const float* __restrict__ b, void* __restrict__ o_)
{
    const int tok = blockIdx.x;
    const int tid = threadIdx.x;
    const float2 v = reinterpret_cast<const float2*>(x + (size_t)tok * D_)[tid];
    float s = v.x + v.y;
#pragma unroll
    for (int off = 1; off < 64; off <<= 1) s += __shfl_xor(s, off);
    __shared__ float red[8];
    const int wv = tid >> 6;
    if ((tid & 63) == 0) red[wv] = s;
    __syncthreads();
    const float mean = (red[0] + red[1] + red[2] + red[3]) * (1.f / D_);
    const float dx = v.x - mean, dy = v.y - mean;
    float q = dx * dx + dy * dy;
#pragma unroll
    for (int off = 1; off < 64; off <<= 1) q += __shfl_xor(q, off);
    if ((tid & 63) == 0) red[4 + wv] = q;
    __syncthreads();
    const float var = (red[4] + red[5] + red[6] + red[7]) * (1.f / D_);
    const float r = rsqrtf(var + 1e-5f);
    const int d0 = tid * 2;
    const float o0 = dx * r * w[d0] + b[d0];
    const float o1 = dy * r * w[d0 + 1] + b[d0 + 1];
    if (BF16OUT) {
        unsigned short* o = (unsigned short*)o_;
        o[(size_t)tok * D_ + d0] = f2bs(o0);
        o[(size_t)tok * D_ + d0 + 1] = f2bs(o1);
    } else {
        float* o = (float*)o_;
        o[(size_t)tok * D_ + d0] = o0;
        o[(size_t)tok * D_ + d0 + 1] = o1;
    }
}

// ---------------------------------------------------------------------------
// MFMA bf16 GEMM: C[M,N] = A[M,K] @ W[N,K]^T, W pre-converted bf16.
// 4 waves 2x2 per block; each wave (MR*16)x(NR*16).
// EPI 0: store fp32; 1: softplus(val+bias[n]); 2: C += val (residual);
//     3: in_proj split-store (col<DI -> xm fp32; col>=DI -> zs=silu bf16)
// AF32: A fp32 (convert on the fly)
// ---------------------------------------------------------------------------
template <int MR, int NR, int EPI, bool AF32>
__global__ __launch_bounds__(256) void gemm2(
    const void* __restrict__ A_, int lda,
    const unsigned short* __restrict__ W, const float* __restrict__ bias,
    float* __restrict__ C, unsigned short* __restrict__ C2, int N, int K)
{
    const int lane = threadIdx.x & 63, wid = threadIdx.x >> 6;
    const int r = lane & 15, kq = lane >> 4;
    const int wm = blockIdx.y * (2 * MR * 16) + (wid >> 1) * (MR * 16);
    const int wn = blockIdx.x * (2 * NR * 16) + (wid & 1) * (NR * 16);
    const float* Af = (const float*)A_;
    const unsigned short* Ab = (const unsigned short*)A_;
    f32x4 acc[MR][NR] = {};
    for (int k0 = 0; k0 < K; k0 += 32) {
        bf16x8 a[MR], b[NR];
#pragma unroll
        for (int i = 0; i < MR; ++i) {
            const int row = wm + i * 16 + r;
            if (AF32) {
                const float4* p = (const float4*)(Af + (size_t)row * lda + k0 + kq * 8);
                a[i] = cvt8(p[0], p[1]);
            } else {
                a[i] = *(const bf16x8*)(Ab + (size_t)row * lda + k0 + kq * 8);
            }
        }
#pragma unroll
        for (int j = 0; j < NR; ++j) {
            const int row = wn + j * 16 + r;
            b[j] = *(const bf16x8*)(W + (size_t)row * K + k0 + kq * 8);
        }
#pragma unroll
        for (int i = 0; i < MR; ++i)
#pragma unroll
            for (int j = 0; j < NR; ++j)
                acc[i][j] = __builtin_amdgcn_mfma_f32_16x16x32_bf16(a[i], b[j], acc[i][j], 0, 0, 0);
    }
    // C/D layout: col = lane&15, row = (lane>>4)*4 + reg
#pragma unroll
    for (int i = 0; i < MR; ++i)
#pragma unroll
        for (int j = 0; j < NR; ++j)
#pragma unroll
            for (int g = 0; g < 4; ++g) {
                const int row = wm + i * 16 + kq * 4 + g;
                const int col = wn + j * 16 + r;
                float val = acc[i][j][g];
                if (EPI == 3) {
                    if (col < DI_) C[(size_t)row * DI_ + col] = val;
                    else C2[(size_t)row * DI_ + (col - DI_)] = f2bs(silu_f(val));
                } else if (EPI == 1) {
                    C[(size_t)row * N + col] = softplus_f(val + bias[col]);
                } else if (EPI == 2) {
                    C[(size_t)row * N + col] += val;
                } else {
                    C[(size_t)row * N + col] = val;
                }
            }
}

// ---------------------------------------------------------------------------
// xp GEMM fused: dbc[M=1024, 64] = xc @ xp_w^T, 4-way in-block split-K
// block = 16 rows; 4 waves each do K-quarter (256) of 16x64; LDS reduce.
// ---------------------------------------------------------------------------
__global__ __launch_bounds__(256) void xp_kernel(
    const unsigned short* __restrict__ xcb, const unsigned short* __restrict__ Wb,
    float* __restrict__ dbc)
{
    __shared__ float red[4][16][64];
    const int tid = threadIdx.x;
    const int wid = tid >> 6, lane = tid & 63;
    const int r = lane & 15, kq = lane >> 4;
    const int m0 = blockIdx.x * 16;
    f32x4 acc[4] = {};
    const int k00 = wid * 256;
#pragma unroll
    for (int ks = 0; ks < 8; ++ks) {
        const int k0 = k00 + ks * 32;
        const bf16x8 a = *(const bf16x8*)(xcb + (size_t)(m0 + r) * DI_ + k0 + kq * 8);
#pragma unroll
        for (int j = 0; j < 4; ++j) {
            const bf16x8 b = *(const bf16x8*)(Wb + (size_t)(j * 16 + r) * DI_ + k0 + kq * 8);
            acc[j] = __builtin_amdgcn_mfma_f32_16x16x32_bf16(a, b, acc[j], 0, 0, 0);
        }
    }
#pragma unroll
    for (int j = 0; j < 4; ++j)
#pragma unroll
        for (int g = 0; g < 4; ++g)
            red[wid][kq * 4 + g][j * 16 + r] = acc[j][g];
    __syncthreads();
    for (int i = tid; i < 1024; i += 256) {
        const int row = i >> 6, col = i & 63;
        const float s = red[0][row][col] + red[1][row][col] +
                        red[2][row][col] + red[3][row][col];
        dbc[(size_t)(m0 + row) * 64 + col] = s;
    }
}

// ---------------------------------------------------------------------------
// Causal depthwise conv1d (DC=4) + SiLU -> bf16 (reads xm fp32, stride DI)
// ---------------------------------------------------------------------------
__global__ __launch_bounds__(256) void conv_silu_kernel(
    const float* __restrict__ xm, const float* __restrict__ cw,
    const float* __restrict__ cb, unsigned short* __restrict__ xcb)
{
    const int idx = blockIdx.x * 256 + threadIdx.x;
    const int d = idx & (DI_ - 1);
    const int bt = idx >> 10;
    const int t = bt & (T_ - 1);
    float acc = cb[d];
#pragma unroll
    for (int k = 0; k < DC_; ++k) {
        const int tt = t - (DC_ - 1) + k;
        if (tt >= 0) acc += cw[d * DC_ + k] * xm[(size_t)(bt - t + tt) * DI_ + d];
    }
    xcb[idx] = f2bs(silu_f(acc));
}

// ---------------------------------------------------------------------------
// Chunked selective scan (3 passes as before); p3 reads silu(z) bf16
// ---------------------------------------------------------------------------
__global__ __launch_bounds__(256) void scan_p1_kernel(
    const float* __restrict__ dlt, const unsigned short* __restrict__ xcb,
    const float* __restrict__ dbc, const float* __restrict__ A_log,
    float* __restrict__ P, float* __restrict__ S)
{
    const int tid = threadIdx.x;
    const int n = tid & 15;
    const int g = blockIdx.x * 16 + (tid >> 4);
    const int d = g & (DI_ - 1);
    const int c = (g >> 10) & 7;
    const int b = g >> 13;
    const float Av = -__expf(A_log[d * N_ + n]);
    const int t0 = c * TC_;
    const float* dl = dlt + ((size_t)b * T_ + t0) * DI_ + d;
    const unsigned short* up = xcb + ((size_t)b * T_ + t0) * DI_ + d;
    const float* bc = dbc + ((size_t)b * T_ + t0) * 64;
    float h = 0.f, Pp = 1.f;
#pragma unroll 4
    for (int t = 0; t < TC_; ++t) {
        const float dt = dl[(size_t)t * DI_];
        const float ut = bs2f(up[(size_t)t * DI_]);
        const float Bn = bc[t * 64 + R_ + n];
        const float dA = __expf(dt * Av);
        h = dA * h + dt * Bn * ut;
        Pp *= dA;
    }
    P[(size_t)g * 16 + n] = Pp;
    S[(size_t)g * 16 + n] = h;
}

__global__ __launch_bounds__(256) void scan_p2_kernel(
    const float* __restrict__ P, float* __restrict__ S)
{
    const int i = blockIdx.x * 256 + threadIdx.x;   // 65536 = B*DI*N
    const int n = i & 15, d = (i >> 4) & (DI_ - 1), b = i >> 14;
    float h = 0.f;
#pragma unroll
    for (int c = 0; c < CH_; ++c) {
        const size_t idx = ((size_t)((b * 8 + c) * 1024 + d)) * 16 + n;
        const float t = P[idx] * h + S[idx];
        S[idx] = h;
        h = t;
    }
}

__global__ __launch_bounds__(256) void scan_p3_kernel(
    const float* __restrict__ dlt, const unsigned short* __restrict__ xcb,
    const float* __restrict__ dbc, const unsigned short* __restrict__ zs,
    const float* __restrict__ A_log, const float* __restrict__ Dp,
    const float* __restrict__ S, unsigned short* __restrict__ ygb)
{
    const int tid = threadIdx.x;
    const int n = tid & 15;
    const int g = blockIdx.x * 16 + (tid >> 4);
    const int d = g & (DI_ - 1);
    const int c = (g >> 10) & 7;
    const int b = g >> 13;
    const float Av = -__expf(A_log[d * N_ + n]);
    const float Dd = Dp[d];
    const int t0 = c * TC_;
    const float* dl = dlt + ((size_t)b * T_ + t0) * DI_ + d;
    const unsigned short* up = xcb + ((size_t)b * T_ + t0) * DI_ + d;
    const float* bc = dbc + ((size_t)b * T_ + t0) * 64;
    const unsigned short* zp = zs + ((size_t)b * T_ + t0) * DI_ + d;
    unsigned short* yp = ygb + ((size_t)b * T_ + t0) * DI_ + d;
    float h = S[(size_t)g * 16 + n];
#pragma unroll 4
    for (int t = 0; t < TC_; ++t) {
        const float dt = dl[(size_t)t * DI_];
        const float ut = bs2f(up[(size_t)t * DI_]);
        const float Bn = bc[t * 64 + R_ + n];
        const float Cn = bc[t * 64 + R_ + N_ + n];
        h = __expf(dt * Av) * h + dt * Bn * ut;
        float p = h * Cn;
        p += __shfl_xor(p, 1);
        p += __shfl_xor(p, 2);
        p += __shfl_xor(p, 4);
        p += __shfl_xor(p, 8);
        if (n == 0) {
            const float zv = bs2f(zp[(size_t)t * DI_]);
            yp[(size_t)t * DI_] = f2bs((p + ut * Dd) * zv);
        }
    }
}

// ---------------------------------------------------------------------------
// Heads
// ---------------------------------------------------------------------------
__global__ __launch_bounds__(256) void heads_kernel(
    const float* __restrict__ xn,
    const float* __restrict__ ps_w, const float* __restrict__ ps_b,
    const float* __restrict__ pa_w, const float* __restrict__ pa_b,
    float* __restrict__ out)
{
    const int idx = blockIdx.x * 4 + (threadIdx.x >> 6);
    const int lane = threadIdx.x & 63;
    const int bl = idx / 23, j = idx % 23;
    const float* tok;
    const float* wrow;
    float bias;
    float* dst;
    if (j < SD_) {
        tok = xn + ((size_t)bl * 4 + 3) * D_;
        wrow = ps_w + (size_t)j * D_;
        bias = ps_b[j];
        dst = out + (size_t)bl * SD_ + j;
    } else {
        const int jj = j - SD_;
        tok = xn + ((size_t)bl * 4 + 2) * D_;
        wrow = pa_w + (size_t)jj * D_;
        bias = pa_b[jj];
        dst = out + (size_t)B_ * L_ * SD_ + (size_t)bl * AD_ + jj;
    }
    float s = 0.f;
    for (int dd = lane; dd < D_; dd += 64) s += tok[dd] * wrow[dd];
#pragma unroll
    for (int off = 1; off < 64; off <<= 1) s += __shfl_xor(s, off);
    if (lane == 0) *dst = s + bias;
}

// ---------------------------------------------------------------------------
extern "C" void kernel_launch(void* const* d_in, const int* in_sizes, int n_in,
                              void* d_out, int out_size, void* d_ws, size_t ws_size,
                              hipStream_t stream)
{
    const float* states  = (const float*)d_in[0];
    const float* actions = (const float*)d_in[1];
    const float* rtg     = (const float*)d_in[2];
    const float* ctg     = (const float*)d_in[3];
    const int*   ts      = (const int*)d_in[4];
    const float* es_w = (const float*)d_in[5];  const float* es_b = (const float*)d_in[6];
    const float* ea_w = (const float*)d_in[7];  const float* ea_b = (const float*)d_in[8];
    const float* er_w = (const float*)d_in[9];  const float* er_b = (const float*)d_in[10];
    const float* ec_w = (const float*)d_in[11]; const float* ec_b = (const float*)d_in[12];
    const float* et_w = (const float*)d_in[13];
    const float* ln_w = (const float*)d_in[14]; const float* ln_b = (const float*)d_in[15];
    const float* in_w = (const float*)d_in[16];
    const float* conv_w = (const float*)d_in[17]; const float* conv_b = (const float*)d_in[18];
    const float* xp_w = (const float*)d_in[19];
    const float* dtp_w = (const float*)d_in[20]; const float* dtp_b = (const float*)d_in[21];
    const float* A_log = (const float*)d_in[22]; const float* Dp = (const float*)d_in[23];
    const float* out_w = (const float*)d_in[24];
    const float* fn_w = (const float*)d_in[25]; const float* fn_b = (const float*)d_in[26];
    const float* ps_w = (const float*)d_in[27]; const float* ps_b = (const float*)d_in[28];
    const float* pa_w = (const float*)d_in[29]; const float* pa_b = (const float*)d_in[30];
    float* out = (float*)d_out;

    // workspace layout
    float* ws   = (float*)d_ws;
    float* x    = ws;                   // 524288
    float* xn   = x + 524288;           // 524288 (final LN out; P aliases during layers)
    float* P    = xn;
    float* xm   = xn + 524288;          // 1048576 (conv input, fp32)
    float* dbc  = xm + 1048576;         // 65536
    float* dlt  = dbc + 65536;          // 1048576
    float* S    = dlt + 1048576;        // 524288
    unsigned short* xnb = (unsigned short*)(S + 524288);  // 524288
    unsigned short* xcb = xnb + 524288;                   // 1048576
    unsigned short* ygb = xcb + 1048576;                  // 1048576
    unsigned short* zs  = ygb + 1048576;                  // 1048576
    unsigned short* wb  = zs + 1048576;                   // NW_TOT bf16 weights
    unsigned short* wb_in  = wb;
    unsigned short* wb_out = wb + NW_IN;
    unsigned short* wb_xp  = wb + NW_IN + NW_OUT;
    unsigned short* wb_dtp = wb + NW_IN + NW_OUT + NW_XP;

    wcvt_kernel<<<NW_TOT / 4 / 256, 256, 0, stream>>>(in_w, out_w, xp_w, dtp_w, wb);
    embed_kernel<<<B_ * L_, D_, 0, stream>>>(states, actions, rtg, ctg, ts,
        es_w, es_b, ea_w, ea_b, er_w, er_b, ec_w, ec_b, et_w, x);

    for (int i = 0; i < NL_; ++i) {
        ln_kernel<true><<<B_ * T_, 256, 0, stream>>>(x, ln_w + i * D_, ln_b + i * D_, xnb);
        // in_proj: xm fp32 + silu(z) bf16 in one pass (1024 x 2048 x 512)
        gemm2<2, 4, 3, false><<<dim3(16, 16), 256, 0, stream>>>(
            xnb, D_, wb_in + (size_t)i * 2 * DI_ * D_, nullptr, xm, zs, 2 * DI_, D_);
        conv_silu_kernel<<<(B_ * T_ * DI_) / 256, 256, 0, stream>>>(
            xm, conv_w + i * DI_ * DC_, conv_b + i * DI_, xcb);
        // dbc = xc @ xp_w^T (fused split-K)
        xp_kernel<<<64, 256, 0, stream>>>(xcb, wb_xp + (size_t)i * 64 * DI_, dbc);
        // delta = softplus(dbc[:, :32] @ dtp_w^T + dtp_b)
        gemm2<2, 2, 1, true><<<dim3(16, 16), 256, 0, stream>>>(
            dbc, 64, wb_dtp + (size_t)i * DI_ * R_, dtp_b + i * DI_, dlt, nullptr, DI_, R_);
        // chunked scan + gate
        scan_p1_kernel<<<2048, 256, 0, stream>>>(
            dlt, xcb, dbc, A_log + (size_t)i * DI_ * N_, P, S);
        scan_p2_kernel<<<256, 256, 0, stream>>>(P, S);
        scan_p3_kernel<<<2048, 256, 0, stream>>>(
            dlt, xcb, dbc, zs, A_log + (size_t)i * DI_ * N_, Dp + i * DI_, S, ygb);
        // x += yg @ out_w^T  (1024 x 512 x 1024)
        gemm2<1, 2, 2, false><<<dim3(8, 32), 256, 0, stream>>>(
            ygb, DI_, wb_out + (size_t)i * D_ * DI_, nullptr, x, nullptr, D_, DI_);
    }

    ln_kernel<false><<<B_ * T_, 256, 0, stream>>>(x, fn_w, fn_b, xn);
    heads_kernel<<<(B_ * L_ * 23) / 4, 256, 0, stream>>>(xn, ps_w, ps_b, pa_w, pa_b, out);
}